// Round 1
// baseline (966.936 us; speedup 1.0000x reference)
//
#include <hip/hip_runtime.h>
#include <math.h>
#include <stdint.h>

#define B_   2048
#define NS_  128
#define D_   1024
#define K_   8
#define DH_  512
#define G3_  3072

typedef unsigned short u16;
typedef short bf16x8 __attribute__((ext_vector_type(8)));
typedef float f32x4 __attribute__((ext_vector_type(4)));

__device__ __forceinline__ float bf2f(u16 u) {
  union { unsigned i; float f; } v; v.i = ((unsigned)u) << 16; return v.f;
}
__device__ __forceinline__ u16 f2bf(float f) {
  unsigned x = __float_as_uint(f);
  return (u16)((x + 0x7fffu + ((x >> 16) & 1u)) >> 16);
}

#define AS1C(p) ((const __attribute__((address_space(1))) void*)(uintptr_t)(p))
#define AS3(p)  ((__attribute__((address_space(3))) void*)(unsigned)(uintptr_t)(p))

// ---------------- fused S->S_new copy + slot mean (f64 accum) ----------------
__global__ __launch_bounds__(256)
void sp_copy_mean(const float* __restrict__ S, float* __restrict__ Snew,
                  float* __restrict__ mean, int do_copy) {
  const int b = blockIdx.x, t = threadIdx.x;
  const int d0 = t * 4;
  const float* src = S + (size_t)b * NS_ * D_ + d0;
  float* dst = Snew + (size_t)b * NS_ * D_ + d0;
  double ax = 0, ay = 0, az = 0, aw = 0;
  if (do_copy) {
    for (int s = 0; s < NS_; ++s) {
      float4 v = *(const float4*)(src + (size_t)s * D_);
      *(float4*)(dst + (size_t)s * D_) = v;
      ax += v.x; ay += v.y; az += v.z; aw += v.w;
    }
  } else {
    for (int s = 0; s < NS_; ++s) {
      float4 v = *(const float4*)(src + (size_t)s * D_);
      ax += v.x; ay += v.y; az += v.z; aw += v.w;
    }
  }
  float4 m4;
  m4.x = (float)(ax * (1.0 / 128.0)); m4.y = (float)(ay * (1.0 / 128.0));
  m4.z = (float)(az * (1.0 / 128.0)); m4.w = (float)(aw * (1.0 / 128.0));
  *(float4*)&mean[(size_t)b * D_ + d0] = m4;
}

// ---------------- f32 -> bf16 convert ----------------
__global__ __launch_bounds__(256)
void sp_f32_to_bf16(const float* __restrict__ src, u16* __restrict__ dst, int n4) {
  int i = blockIdx.x * 256 + threadIdx.x;
  if (i >= n4) return;
  float4 v = ((const float4*)src)[i];
  ushort4 o;
  o.x = f2bf(v.x); o.y = f2bf(v.y); o.z = f2bf(v.z); o.w = f2bf(v.w);
  ((ushort4*)dst)[i] = o;
}

// ---------------- routing GEMM1: h = gelu(ctx @ w1^T + b1), f64 accum ----------------
// ctx = [x | mean], M=2048, N=512, K=2048. BM=64 BN=32 BK=16.
__global__ __launch_bounds__(256)
void sp_gemm1(const float* __restrict__ x, const float* __restrict__ mean,
              const float* __restrict__ w1, const float* __restrict__ bias1,
              float* __restrict__ h) {
  __shared__ float As[16][68];
  __shared__ float Bs[16][36];
  const int t = threadIdx.x;
  const int m0 = blockIdx.y * 64, n0 = blockIdx.x * 32;
  const int tx = t & 15, ty = t >> 4;
  double acc[4][2] = {};
  const int sr = t >> 2, sc = (t & 3) * 4;
  for (int k0 = 0; k0 < 2 * D_; k0 += 16) {
    const float* src = (k0 < D_) ? (x + k0) : (mean + (k0 - D_));
    float4 va = *(const float4*)&src[(size_t)(m0 + sr) * D_ + sc];
    As[sc + 0][sr] = va.x; As[sc + 1][sr] = va.y; As[sc + 2][sr] = va.z; As[sc + 3][sr] = va.w;
    if (t < 128) {
      const int bn = t >> 2, bc = (t & 3) * 4;
      float4 vb = *(const float4*)&w1[(size_t)(n0 + bn) * (2 * D_) + k0 + bc];
      Bs[bc + 0][bn] = vb.x; Bs[bc + 1][bn] = vb.y; Bs[bc + 2][bn] = vb.z; Bs[bc + 3][bn] = vb.w;
    }
    __syncthreads();
    #pragma unroll
    for (int kk = 0; kk < 16; ++kk) {
      float4 a = *(const float4*)&As[kk][ty * 4];
      float2 bb = *(const float2*)&Bs[kk][tx * 2];
      double b0 = (double)bb.x, b1d = (double)bb.y;
      acc[0][0] += (double)a.x * b0; acc[0][1] += (double)a.x * b1d;
      acc[1][0] += (double)a.y * b0; acc[1][1] += (double)a.y * b1d;
      acc[2][0] += (double)a.z * b0; acc[2][1] += (double)a.z * b1d;
      acc[3][0] += (double)a.w * b0; acc[3][1] += (double)a.w * b1d;
    }
    __syncthreads();
  }
  #pragma unroll
  for (int i = 0; i < 4; ++i) {
    #pragma unroll
    for (int j = 0; j < 2; ++j) {
      int r = m0 + ty * 4 + i, c = n0 + tx * 2 + j;
      float v = (float)acc[i][j] + bias1[c];
      v = 0.5f * v * (1.0f + erff(v * 0.70710678118654752f));
      h[(size_t)r * DH_ + c] = v;
    }
  }
}

// ---------------- logits + top-8 + softmax (one wave per row) ----------------
__global__ __launch_bounds__(64)
void sp_route_topk(const float* __restrict__ h, const float* __restrict__ w2,
                   const float* __restrict__ b2, const float* __restrict__ tau,
                   int* __restrict__ tki, float* __restrict__ tkw) {
  __shared__ float hs[DH_];
  const int b = blockIdx.x, l = threadIdx.x;
  *(float4*)&hs[l * 4] = *(const float4*)&h[(size_t)b * DH_ + l * 4];
  *(float4*)&hs[256 + l * 4] = *(const float4*)&h[(size_t)b * DH_ + 256 + l * 4];
  __syncthreads();
  const double invd = 1.0 / ((double)fabsf(tau[0]) + 0.1);
  float v[2]; int id[2];
  #pragma unroll
  for (int c = 0; c < 2; ++c) {
    const int n = c * 64 + l;
    const float* wr = &w2[(size_t)n * DH_];
    double s = 0.0;
    for (int j = 0; j < DH_; j += 4) {
      float4 w4 = *(const float4*)&wr[j];
      s += (double)hs[j] * (double)w4.x;
      s += (double)hs[j + 1] * (double)w4.y;
      s += (double)hs[j + 2] * (double)w4.z;
      s += (double)hs[j + 3] * (double)w4.w;
    }
    v[c] = (float)((s + (double)b2[n]) * invd);
    id[c] = n;
  }
  float m0f = 0.f, sum = 0.f, mye = 0.f; int myi = 0;
  for (int r = 0; r < 8; ++r) {
    float mv; int mi;
    if (v[1] > v[0]) { mv = v[1]; mi = id[1]; } else { mv = v[0]; mi = id[0]; }
    #pragma unroll
    for (int off = 32; off > 0; off >>= 1) {
      float ov = __shfl_xor(mv, off);
      int oi = __shfl_xor(mi, off);
      if (ov > mv || (ov == mv && oi < mi)) { mv = ov; mi = oi; }
    }
    if (r == 0) m0f = mv;
    float er = expf(mv - m0f);
    sum += er;
    if (l == r) { mye = er; myi = mi; }
    if (mi == id[0]) v[0] = -3.0e38f;
    if (mi == id[1]) v[1] = -3.0e38f;
  }
  if (l < 8) { tki[b * K_ + l] = myi; tkw[b * K_ + l] = mye / sum; }
}

// ---------------- gather selected slot rows -> bf16 ----------------
__global__ __launch_bounds__(256)
void sp_gather(const float* __restrict__ S, const int* __restrict__ tki,
               u16* __restrict__ slotb) {
  const int blk = blockIdx.x;
  const int b = blk >> 3, k = blk & 7;
  const int s = tki[b * K_ + k];
  const int t = threadIdx.x;
  float4 v = *(const float4*)&S[((size_t)b * NS_ + s) * D_ + t * 4];
  ushort4 o;
  o.x = f2bf(v.x); o.y = f2bf(v.y); o.z = f2bf(v.z); o.w = f2bf(v.w);
  *(ushort4*)&slotb[((size_t)b * K_ + k) * D_ + t * 4] = o;
}

// ---------------- bf16 TN MFMA GEMM: C[M,N] = A[M,K] * B[N,K]^T ----------------
// 128x128 tile, BK=32, 4 waves, 16x16x32 MFMA, global_load_lds staging.
// EPI: 0=f32 store, 1=bf16 store, 2=bias+f32, 3=bias+bf16
template<int EPI>
__global__ __launch_bounds__(256)
void sp_gemm_bf16(const u16* __restrict__ A, const u16* __restrict__ Bm,
                  void* __restrict__ Cv, const float* __restrict__ bias,
                  int M, int N, int Kd) {
  __shared__ u16 lA[128 * 32];
  __shared__ u16 lB[128 * 32];
  const int t = threadIdx.x;
  const int lane = t & 63;
  const int w = t >> 6;
  const int wm = w >> 1, wn = w & 1;
  const int m0 = blockIdx.y * 128, n0 = blockIdx.x * 128;

  f32x4 acc[4][4] = {};

  const int srow = t >> 2;
  const int scol = (t & 3) * 8;
  const u16* gA0 = A + (size_t)(m0 + srow) * Kd + scol;
  const u16* gA1 = A + (size_t)(m0 + 64 + srow) * Kd + scol;
  const u16* gB0 = Bm + (size_t)(n0 + srow) * Kd + scol;
  const u16* gB1 = Bm + (size_t)(n0 + 64 + srow) * Kd + scol;
  u16* lAw = &lA[(t & 192) * 8];
  u16* lBw = &lB[(t & 192) * 8];

  const int kb = (lane >> 4) * 8;
  const int rA = wm * 64 + (lane & 15);
  const int rB = wn * 64 + (lane & 15);

  for (int k0 = 0; k0 < Kd; k0 += 32) {
    __builtin_amdgcn_global_load_lds(AS1C(gA0 + k0), AS3(lAw), 16, 0, 0);
    __builtin_amdgcn_global_load_lds(AS1C(gA1 + k0), AS3(lAw + 2048), 16, 0, 0);
    __builtin_amdgcn_global_load_lds(AS1C(gB0 + k0), AS3(lBw), 16, 0, 0);
    __builtin_amdgcn_global_load_lds(AS1C(gB1 + k0), AS3(lBw + 2048), 16, 0, 0);
    __syncthreads();
    bf16x8 af[4], bfr[4];
    #pragma unroll
    for (int fm = 0; fm < 4; ++fm)
      af[fm] = *(const bf16x8*)&lA[(rA + fm * 16) * 32 + kb];
    #pragma unroll
    for (int fn = 0; fn < 4; ++fn)
      bfr[fn] = *(const bf16x8*)&lB[(rB + fn * 16) * 32 + kb];
    #pragma unroll
    for (int fm = 0; fm < 4; ++fm) {
      #pragma unroll
      for (int fn = 0; fn < 4; ++fn)
        acc[fm][fn] = __builtin_amdgcn_mfma_f32_16x16x32_bf16(af[fm], bfr[fn], acc[fm][fn], 0, 0, 0);
    }
    __syncthreads();
  }

  #pragma unroll
  for (int fm = 0; fm < 4; ++fm) {
    #pragma unroll
    for (int fn = 0; fn < 4; ++fn) {
      #pragma unroll
      for (int i = 0; i < 4; ++i) {
        const int r = m0 + wm * 64 + fm * 16 + (lane >> 4) * 4 + i;
        const int c = n0 + wn * 64 + fn * 16 + (lane & 15);
        float v = acc[fm][fn][i];
        if constexpr (EPI >= 2) v += bias[c];
        if constexpr (EPI == 0 || EPI == 2)
          ((float*)Cv)[(size_t)r * N + c] = v;
        else
          ((u16*)Cv)[(size_t)r * N + c] = f2bf(v);
      }
    }
  }
}

// ---------------- fused GRU elementwise + scatter + weighted mix ----------------
template<bool DIRECT>
__global__ __launch_bounds__(256)
void sp_gru(const float* __restrict__ gi, const u16* __restrict__ gh,
            const float* __restrict__ S, const int* __restrict__ tki,
            const float* __restrict__ tkw, const float* __restrict__ bih,
            const float* __restrict__ bhh, float* __restrict__ dst,
            u16* __restrict__ umix) {
  const int b = blockIdx.x, t = threadIdx.x;
  const int d0 = t * 4;
  float Gr[4], Gz[4], Gn[4], Hr[4], Hz[4], Hn[4], Um[4] = {0.f, 0.f, 0.f, 0.f};
  {
    const size_t gb = (size_t)b * G3_;
    float4 a, c;
    a = *(const float4*)&gi[gb + d0];          c = *(const float4*)&bih[d0];
    Gr[0]=a.x+c.x; Gr[1]=a.y+c.y; Gr[2]=a.z+c.z; Gr[3]=a.w+c.w;
    a = *(const float4*)&gi[gb + D_ + d0];     c = *(const float4*)&bih[D_ + d0];
    Gz[0]=a.x+c.x; Gz[1]=a.y+c.y; Gz[2]=a.z+c.z; Gz[3]=a.w+c.w;
    a = *(const float4*)&gi[gb + 2 * D_ + d0]; c = *(const float4*)&bih[2 * D_ + d0];
    Gn[0]=a.x+c.x; Gn[1]=a.y+c.y; Gn[2]=a.z+c.z; Gn[3]=a.w+c.w;
    c = *(const float4*)&bhh[d0];          Hr[0]=c.x; Hr[1]=c.y; Hr[2]=c.z; Hr[3]=c.w;
    c = *(const float4*)&bhh[D_ + d0];     Hz[0]=c.x; Hz[1]=c.y; Hz[2]=c.z; Hz[3]=c.w;
    c = *(const float4*)&bhh[2 * D_ + d0]; Hn[0]=c.x; Hn[1]=c.y; Hn[2]=c.z; Hn[3]=c.w;
  }
  #pragma unroll
  for (int k = 0; k < K_; ++k) {
    const int s = tki[b * K_ + k];
    const float wk = tkw[b * K_ + k];
    const float4 sl = *(const float4*)&S[((size_t)b * NS_ + s) * D_ + d0];
    const u16* ghp = gh + ((size_t)b * K_ + k) * G3_ + d0;
    ushort4 r4 = *(const ushort4*)(ghp);
    ushort4 z4 = *(const ushort4*)(ghp + D_);
    ushort4 n4 = *(const ushort4*)(ghp + 2 * D_);
    float slc[4] = { sl.x, sl.y, sl.z, sl.w };
    u16 rr[4] = { r4.x, r4.y, r4.z, r4.w };
    u16 zz[4] = { z4.x, z4.y, z4.z, z4.w };
    u16 nn[4] = { n4.x, n4.y, n4.z, n4.w };
    float uv[4];
    #pragma unroll
    for (int j = 0; j < 4; ++j) {
      float rg = 1.f / (1.f + expf(-(Gr[j] + bf2f(rr[j]) + Hr[j])));
      float zg = 1.f / (1.f + expf(-(Gz[j] + bf2f(zz[j]) + Hz[j])));
      float ng = tanhf(Gn[j] + rg * (bf2f(nn[j]) + Hn[j]));
      uv[j] = (1.f - zg) * ng + zg * slc[j];
      Um[j] += wk * uv[j];
    }
    float4 o; o.x = uv[0]; o.y = uv[1]; o.z = uv[2]; o.w = uv[3];
    if (DIRECT)
      *(float4*)&dst[((size_t)b * NS_ + s) * D_ + d0] = o;
    else
      *(float4*)&dst[((size_t)b * K_ + k) * D_ + d0] = o;
  }
  ushort4 um;
  um.x = f2bf(Um[0]); um.y = f2bf(Um[1]); um.z = f2bf(Um[2]); um.w = f2bf(Um[3]);
  *(ushort4*)&umix[(size_t)b * D_ + d0] = um;
}

// ---------------- variant B: copy S->S_new with scatter of updated rows ----------------
__global__ __launch_bounds__(256)
void sp_copy_scatter(const float* __restrict__ S, const float* __restrict__ upd,
                     const int* __restrict__ tki, float* __restrict__ Snew) {
  const int b = blockIdx.x, t = threadIdx.x;
  const int d0 = t * 4;
  int idx[K_];
  #pragma unroll
  for (int k = 0; k < K_; ++k) idx[k] = tki[b * K_ + k];
  for (int s = 0; s < NS_; ++s) {
    int sk = -1;
    #pragma unroll
    for (int k = 0; k < K_; ++k) if (idx[k] == s) sk = k;
    float4 v;
    if (sk >= 0) v = *(const float4*)&upd[((size_t)b * K_ + sk) * D_ + d0];
    else         v = *(const float4*)&S[((size_t)b * NS_ + s) * D_ + d0];
    *(float4*)&Snew[((size_t)b * NS_ + s) * D_ + d0] = v;
  }
}

extern "C" void kernel_launch(void* const* d_in, const int* in_sizes, int n_in,
                              void* d_out, int out_size, void* d_ws, size_t ws_size,
                              hipStream_t stream) {
  const float* x    = (const float*)d_in[0];
  const float* S    = (const float*)d_in[1];
  const float* w1   = (const float*)d_in[2];
  const float* b1   = (const float*)d_in[3];
  const float* w2   = (const float*)d_in[4];
  const float* b2   = (const float*)d_in[5];
  const float* wih  = (const float*)d_in[6];
  const float* whh  = (const float*)d_in[7];
  const float* bih  = (const float*)d_in[8];
  const float* bhh  = (const float*)d_in[9];
  const float* wval = (const float*)d_in[10];
  const float* bval = (const float*)d_in[11];
  const float* wout = (const float*)d_in[12];
  const float* bout = (const float*)d_in[13];
  const float* tau  = (const float*)d_in[14];

  float* out  = (float*)d_out;
  float* Snew = out + (size_t)B_ * D_;

  const bool bigws = ws_size >= (size_t)205 * 1024 * 1024;
  char* bigbase = bigws ? (char*)d_ws : (char*)Snew;  // variant B: big scratch in S_new region
  size_t bo = 0;
  auto balloc = [&](size_t bytes) -> void* {
    void* p = bigbase + bo; bo += (bytes + 255) & ~(size_t)255; return p;
  };

  float* mean  = (float*)balloc((size_t)B_ * D_ * 4);
  float* h     = (float*)balloc((size_t)B_ * DH_ * 4);
  u16* xb      = (u16*)balloc((size_t)B_ * D_ * 2);
  u16* wihb    = (u16*)balloc((size_t)G3_ * D_ * 2);
  u16* whhb    = (u16*)balloc((size_t)G3_ * D_ * 2);
  u16* wvalb   = (u16*)balloc((size_t)D_ * D_ * 2);
  u16* woutb   = (u16*)balloc((size_t)D_ * D_ * 2);
  float* gi    = (float*)balloc((size_t)B_ * G3_ * 4);
  u16* slotb   = (u16*)balloc((size_t)B_ * K_ * D_ * 2);
  u16* ghb     = (u16*)balloc((size_t)B_ * K_ * G3_ * 2);
  u16* umixb   = (u16*)balloc((size_t)B_ * D_ * 2);
  u16* mixedb  = (u16*)balloc((size_t)B_ * D_ * 2);

  // small buffers always live in d_ws
  char* wsb = (char*)d_ws;
  size_t so = bigws ? bo : 0;
  auto salloc = [&](size_t bytes) -> void* {
    void* p = wsb + so; so += (bytes + 255) & ~(size_t)255; return p;
  };
  int*   tki = (int*)salloc((size_t)B_ * K_ * 4);
  float* tkw = (float*)salloc((size_t)B_ * K_ * 4);
  float* upd = bigws ? nullptr : (float*)salloc((size_t)B_ * K_ * D_ * 4);

  // 1. fused copy + mean (variant B: mean only, S_new region is scratch)
  sp_copy_mean<<<B_, 256, 0, stream>>>(S, Snew, mean, bigws ? 1 : 0);

  // 2. bf16 conversions
  sp_f32_to_bf16<<<(B_ * D_ / 1024), 256, 0, stream>>>(x, xb, B_ * D_ / 4);
  sp_f32_to_bf16<<<(G3_ * D_ / 1024), 256, 0, stream>>>(wih, wihb, G3_ * D_ / 4);
  sp_f32_to_bf16<<<(G3_ * D_ / 1024), 256, 0, stream>>>(whh, whhb, G3_ * D_ / 4);
  sp_f32_to_bf16<<<(D_ * D_ / 1024), 256, 0, stream>>>(wval, wvalb, D_ * D_ / 4);
  sp_f32_to_bf16<<<(D_ * D_ / 1024), 256, 0, stream>>>(wout, woutb, D_ * D_ / 4);

  // 3. routing MLP (fp32 inputs, f64 accumulate)
  sp_gemm1<<<dim3(DH_ / 32, B_ / 64), 256, 0, stream>>>(x, mean, w1, b1, h);
  sp_route_topk<<<B_, 64, 0, stream>>>(h, w2, b2, tau, tki, tkw);

  // 4. gather selected slots (bf16 A for the gh GEMM)
  sp_gather<<<B_ * K_, 256, 0, stream>>>(S, tki, slotb);

  // 5. GRU input/hidden GEMMs (bf16 MFMA)
  sp_gemm_bf16<0><<<dim3(G3_ / 128, B_ / 128), 256, 0, stream>>>(
      xb, wihb, gi, nullptr, B_, G3_, D_);
  sp_gemm_bf16<1><<<dim3(G3_ / 128, (B_ * K_) / 128), 256, 0, stream>>>(
      slotb, whhb, ghb, nullptr, B_ * K_, G3_, D_);

  // 6. GRU elementwise + scatter + weighted mix
  if (bigws)
    sp_gru<true><<<B_, 256, 0, stream>>>(gi, ghb, S, tki, tkw, bih, bhh, Snew, umixb);
  else
    sp_gru<false><<<B_, 256, 0, stream>>>(gi, ghb, S, tki, tkw, bih, bhh, upd, umixb);

  // 7. readout: mixed = umix @ wval^T + bval ; out = mixed @ wout^T + bout
  sp_gemm_bf16<3><<<dim3(D_ / 128, B_ / 128), 256, 0, stream>>>(
      umixb, wvalb, mixedb, bval, B_, D_, D_);
  sp_gemm_bf16<2><<<dim3(D_ / 128, B_ / 128), 256, 0, stream>>>(
      mixedb, woutb, out, bout, B_, D_, D_);

  // 8. variant B: final copy+scatter
  if (!bigws)
    sp_copy_scatter<<<B_, 256, 0, stream>>>(S, upd, tki, Snew);
}